// Round 1
// baseline (279.063 us; speedup 1.0000x reference)
//
#include <hip/hip_runtime.h>
#include <math.h>

#define D 64
#define K 16
#define PP 2
#define NN 65536
#define LOG2PI 1.8378770664093454
#define NOISE 0.1  /* 1/BETA */

#ifdef __HIP_PLATFORM_AMD__
#define ATOMIC_ADD_F64(p, v) unsafeAtomicAdd((p), (v))
#else
#define ATOMIC_ADD_F64(p, v) atomicAdd((p), (v))
#endif

// ---------------- Gram: G = X^T X (f64), X is N x D f32 ----------------
#define CHUNK 256
#define NBLK (NN / CHUNK)  // 256 blocks

__global__ __launch_bounds__(256) void gram_kernel(const float* __restrict__ x,
                                                   double* __restrict__ G) {
    __shared__ float xs[128 * D];  // 32 KB stage
    const int tid = threadIdx.x;
    const int ib = (tid >> 4) << 2;  // row-tile base 0..60
    const int jb = (tid & 15) << 2;  // col-tile base 0..60
    float acc[4][4];
#pragma unroll
    for (int u = 0; u < 4; ++u)
#pragma unroll
        for (int v = 0; v < 4; ++v) acc[u][v] = 0.0f;

    const float4* src = (const float4*)(x + (size_t)blockIdx.x * CHUNK * D);
    float4* dst = (float4*)xs;
    for (int stage = 0; stage < CHUNK / 128; ++stage) {
#pragma unroll
        for (int u = 0; u < 8; ++u)
            dst[tid + 256 * u] = src[stage * 2048 + tid + 256 * u];
        __syncthreads();
        for (int r = 0; r < 128; ++r) {
            const float4 xi = *(const float4*)&xs[r * D + ib];
            const float4 xj = *(const float4*)&xs[r * D + jb];
            float a0[4] = {xi.x, xi.y, xi.z, xi.w};
            float b0[4] = {xj.x, xj.y, xj.z, xj.w};
#pragma unroll
            for (int u = 0; u < 4; ++u)
#pragma unroll
                for (int v = 0; v < 4; ++v)
                    acc[u][v] = fmaf(a0[u], b0[v], acc[u][v]);
        }
        __syncthreads();
    }
#pragma unroll
    for (int u = 0; u < 4; ++u)
#pragma unroll
        for (int v = 0; v < 4; ++v)
            ATOMIC_ADD_F64(&G[(ib + u) * D + (jb + v)], (double)acc[u][v]);
}

// ---------------- Per (a,p) pair: small algebra + quadratic forms ----------------
__global__ __launch_bounds__(256) void pair_kernel(const float* __restrict__ W,
                                                   const int* __restrict__ perms,
                                                   const double* __restrict__ G,
                                                   double* __restrict__ acc_out) {
    const int pair = blockIdx.x;       // a*P + p
    const int m = pair / PP + 1;       // a+1
    const int tid = threadIdx.x;
    const int col = tid & 63;
    const int rq = tid >> 6;           // 0..3 (wave index)

    __shared__ int perm[D];
    __shared__ float Wp[D][K + 1];
    __shared__ double S[D][D + 1];
    __shared__ float Gp[D][D + 1];
    __shared__ double fcol[D];
    __shared__ double qpart[4][D];
    __shared__ double red[D];

    if (tid < D) perm[tid] = perms[pair * D + tid];
    __syncthreads();
    for (int e = tid; e < D * K; e += 256) {
        int i = e >> 4, k = e & (K - 1);
        Wp[i][k] = W[perm[i] * K + k];
    }
    for (int e = tid; e < D * D; e += 256) {
        int i = e >> 6, t = e & 63;
        Gp[i][t] = (float)G[perm[i] * D + perm[t]];
    }
    __syncthreads();
    // S = Wp Wp^T + (1/BETA) I   (f64)
    for (int i = rq; i < D; i += 4) {
        double s = 0.0;
#pragma unroll
        for (int k = 0; k < K; ++k)
            s += (double)Wp[i][k] * (double)Wp[col][k];
        S[i][col] = s + (i == col ? NOISE : 0.0);
    }
    __syncthreads();

    // In-place Gauss-Jordan on rows [m,D): reduce cols [m,D) to I.
    // Afterwards S[m+i][j] (j<m) holds A^T, i.e. A[j][i].
    for (int k = m; k < D; ++k) {
        if (tid < D) fcol[tid] = S[tid][k];
        __syncthreads();
        double pinv = 1.0 / fcol[k];
        double srow = S[k][col] * pinv;
        __syncthreads();
        if (rq == 0) S[k][col] = srow;
        for (int i = m + rq; i < D; i += 4)
            if (i != k) S[i][col] -= fcol[i] * srow;
        __syncthreads();
    }

    // q_j = c^T Gp c with c_j = 1, c_{m+i} = -A[j][i] = -S[m+i][j]
    {
        const int j = col;
        double h[16];
#pragma unroll
        for (int u = 0; u < 16; ++u) {
            int t = m + rq + 4 * u;
            h[u] = (t < D) ? (double)Gp[j][t] : 0.0;
        }
        double hj = (double)Gp[j][j];
        for (int s = m; s < D; ++s) {
            double cs = -S[s][j];
            hj += cs * (double)Gp[s][j];
#pragma unroll
            for (int u = 0; u < 16; ++u) {
                int t = m + rq + 4 * u;
                if (t < D) h[u] += cs * (double)Gp[s][t];
            }
        }
        double q = (rq == 0) ? hj : 0.0;
#pragma unroll
        for (int u = 0; u < 16; ++u) {
            int t = m + rq + 4 * u;
            if (t < D) q += (-S[t][j]) * h[u];
        }
        qpart[rq][col] = q;
    }
    __syncthreads();

    // v_j, per-row term, block sum
    if (tid < D) {
        const int j = tid;
        double tj = 0.0;
        if (j < m) {
            double q = qpart[0][j] + qpart[1][j] + qpart[2][j] + qpart[3][j];
            double v = S[j][j];
            for (int s = m; s < D; ++s)
                v -= S[s][j] * S[j][s];  // A[j][i] * S_mr[j][i]
            tj = -0.5 * log(v) - 0.5 * LOG2PI - 0.5 * q / (v * (double)NN);
        }
        red[j] = tj;
    }
    __syncthreads();
    if (tid == 0) {
        double ssum = 0.0;
        for (int j = 0; j < D; ++j) ssum += red[j];
        ATOMIC_ADD_F64(acc_out, ssum / (double)(PP * m));
    }
}

__global__ void finalize_kernel(const double* __restrict__ acc,
                                float* __restrict__ out) {
    out[0] = -(float)acc[0];
}

extern "C" void kernel_launch(void* const* d_in, const int* in_sizes, int n_in,
                              void* d_out, int out_size, void* d_ws, size_t ws_size,
                              hipStream_t stream) {
    const float* x = (const float*)d_in[0];
    const float* W = (const float*)d_in[1];
    const int* perms = (const int*)d_in[2];
    double* G = (double*)d_ws;
    double* acc = G + D * D;

    hipMemsetAsync(d_ws, 0, (D * D + 1) * sizeof(double), stream);
    gram_kernel<<<NBLK, 256, 0, stream>>>(x, G);
    pair_kernel<<<D * PP, 256, 0, stream>>>(W, perms, G, acc);
    finalize_kernel<<<1, 1, 0, stream>>>(acc, (float*)d_out);
}

// Round 2
// 147.826 us; speedup vs baseline: 1.8878x; 1.8878x over previous
//
#include <hip/hip_runtime.h>
#include <math.h>

#define D 64
#define K 16
#define PP 2
#define NN 65536
#define LOG2PI 1.8378770664093454
#define NOISE 0.1  /* 1/BETA */

#ifdef __HIP_PLATFORM_AMD__
#define ATOMIC_ADD_F64(p, v) unsafeAtomicAdd((p), (v))
#else
#define ATOMIC_ADD_F64(p, v) atomicAdd((p), (v))
#endif

// ---------------- Gram partials: per-block 64x64 f32 tile, no atomics --------
#define CHUNK 256
#define NBLK (NN / CHUNK)  // 256 chunks

__global__ __launch_bounds__(256) void gram_kernel(const float* __restrict__ x,
                                                   float* __restrict__ part,
                                                   int npart) {
    __shared__ float xs[128 * D];  // 32 KB stage
    const int tid = threadIdx.x;
    const int ib = (tid >> 4) << 2;
    const int jb = (tid & 15) << 2;
    float acc[4][4];
#pragma unroll
    for (int u = 0; u < 4; ++u)
#pragma unroll
        for (int v = 0; v < 4; ++v) acc[u][v] = 0.0f;

    for (int cb = blockIdx.x; cb < NBLK; cb += npart) {
        const float4* src = (const float4*)(x + (size_t)cb * CHUNK * D);
        float4* dst = (float4*)xs;
        for (int stage = 0; stage < CHUNK / 128; ++stage) {
#pragma unroll
            for (int u = 0; u < 8; ++u)
                dst[tid + 256 * u] = src[stage * 2048 + tid + 256 * u];
            __syncthreads();
            for (int r = 0; r < 128; ++r) {
                const float4 xi = *(const float4*)&xs[r * D + ib];
                const float4 xj = *(const float4*)&xs[r * D + jb];
                float a0[4] = {xi.x, xi.y, xi.z, xi.w};
                float b0[4] = {xj.x, xj.y, xj.z, xj.w};
#pragma unroll
                for (int u = 0; u < 4; ++u)
#pragma unroll
                    for (int v = 0; v < 4; ++v)
                        acc[u][v] = fmaf(a0[u], b0[v], acc[u][v]);
            }
            __syncthreads();
        }
    }
    float* p = part + (size_t)blockIdx.x * (D * D);
#pragma unroll
    for (int u = 0; u < 4; ++u)
#pragma unroll
        for (int v = 0; v < 4; ++v)
            p[(ib + u) * D + (jb + v)] = acc[u][v];
}

__global__ __launch_bounds__(256) void reduce_kernel(const float* __restrict__ part,
                                                     int npart,
                                                     float* __restrict__ Gf) {
    const int e = blockIdx.x * 256 + threadIdx.x;  // 4096 entries, grid=16
    double s = 0.0;
    for (int b = 0; b < npart; ++b) s += (double)part[(size_t)b * (D * D) + e];
    Gf[e] = (float)s;
}

// ---------------- Per (a,p) pair via Woodbury (M is 16x16) ----------------
__global__ __launch_bounds__(256) void pair_kernel(const float* __restrict__ W,
                                                   const int* __restrict__ perms,
                                                   const float* __restrict__ Gf,
                                                   double* __restrict__ acc_out) {
    const int pair = blockIdx.x;   // a*P + p
    const int m = pair / PP + 1;   // a+1
    const int tid = threadIdx.x;

    __shared__ int perm[D];
    __shared__ float Wp[D][K + 1];
    __shared__ float Gp[D][D + 1];
    __shared__ double Maug[K][2 * K + 1];  // [M | I] -> [I | M^-1]
    __shared__ double U[K][D + 1];         // U[:,j] = M^-1 w_j
    __shared__ double Y[K][D + 1];         // Y = Wr^T Gp[m:,:]
    __shared__ double Z[K][K + 1];         // Z = Y[:,m:] Wr
    __shared__ double qp[4][D];
    __shared__ double vp[4][D];
    __shared__ double red[D];

    if (tid < D) perm[tid] = perms[pair * D + tid];
    __syncthreads();
    for (int e = tid; e < D * K; e += 256) {
        int i = e >> 4, k = e & (K - 1);
        Wp[i][k] = W[perm[i] * K + k];
    }
    for (int e = tid; e < D * D; e += 256) {
        int i = e >> 6, t = e & 63;
        Gp[i][t] = Gf[perm[i] * D + perm[t]];
    }
    __syncthreads();

    // M = eps*I + Wr^T Wr  (16x16, f64), augmented with I
    {
        int k1 = tid >> 4, k2 = tid & 15;
        if (tid < K * K) {
            double s = (k1 == k2) ? NOISE : 0.0;
            for (int sr = m; sr < D; ++sr)
                s += (double)Wp[sr][k1] * (double)Wp[sr][k2];
            Maug[k1][k2] = s;
            Maug[k1][K + k2] = (k1 == k2) ? 1.0 : 0.0;
        }
    }
    __syncthreads();

    // Gauss-Jordan invert M (SPD, no pivot). 16 rows x 32 cols, 2 rows/thread.
    {
        const int c = tid & 31;
        const int r0 = tid >> 5;  // 0..7; also handles r0+8
        for (int k = 0; k < K; ++k) {
            double a0 = Maug[r0][c], a1 = Maug[r0 + 8][c];
            double f0 = Maug[r0][k], f1 = Maug[r0 + 8][k];
            double srow = Maug[k][c] / Maug[k][k];
            __syncthreads();
            Maug[r0][c] = (r0 == k) ? srow : a0 - f0 * srow;
            Maug[r0 + 8][c] = (r0 + 8 == k) ? srow : a1 - f1 * srow;
            __syncthreads();
        }
    }

    // U[k][j] = sum_k2 Minv[k][k2] * Wp[j][k2]
    {
        const int j = tid & 63;
        const int kb = tid >> 6;  // 0..3
#pragma unroll
        for (int u = 0; u < 4; ++u) {
            int k = kb + 4 * u;
            double s = 0.0;
#pragma unroll
            for (int k2 = 0; k2 < K; ++k2)
                s += Maug[k][K + k2] * (double)Wp[j][k2];
            U[k][j] = s;
        }
        // Y[k][j] = sum_{s>=m} Wp[s][k] * Gp[s][j]
#pragma unroll
        for (int u = 0; u < 4; ++u) {
            int k = kb + 4 * u;
            double s = 0.0;
            for (int sr = m; sr < D; ++sr)
                s += (double)Wp[sr][k] * (double)Gp[sr][j];
            Y[k][j] = s;
        }
    }
    __syncthreads();

    // Z[k1][k2] = sum_{s>=m} Y[k1][s] * Wp[s][k2]
    {
        int k1 = tid >> 4, k2 = tid & 15;
        if (tid < K * K) {
            double s = 0.0;
            for (int sr = m; sr < D; ++sr)
                s += Y[k1][sr] * (double)Wp[sr][k2];
            Z[k1][k2] = s;
        }
    }
    __syncthreads();

    // per-j partials: dv = w_j.u_j ; t1 = u_j.Y[:,j] ; t2 = u_j^T Z u_j
    {
        const int lane4 = tid & 3;
        const int j = tid >> 2;
        double dv = 0.0, t1 = 0.0, t2 = 0.0;
        for (int k1 = lane4; k1 < K; k1 += 4) {
            double uj = U[k1][j];
            dv += (double)Wp[j][k1] * uj;
            t1 += uj * Y[k1][j];
            double zs = 0.0;
#pragma unroll
            for (int k2 = 0; k2 < K; ++k2) zs += Z[k1][k2] * U[k2][j];
            t2 += uj * zs;
        }
        vp[lane4][j] = dv;
        qp[lane4][j] = -2.0 * t1 + t2;
    }
    __syncthreads();

    if (tid < D) {
        const int j = tid;
        double tj = 0.0;
        if (j < m) {
            double dv = vp[0][j] + vp[1][j] + vp[2][j] + vp[3][j];
            double v = NOISE * (1.0 + dv);
            double q = (double)Gp[j][j] + qp[0][j] + qp[1][j] + qp[2][j] + qp[3][j];
            tj = -0.5 * log(v) - 0.5 * LOG2PI - 0.5 * q / (v * (double)NN);
        }
        red[j] = tj;
    }
    __syncthreads();
    if (tid == 0) {
        double ssum = 0.0;
        for (int j = 0; j < D; ++j) ssum += red[j];
        ATOMIC_ADD_F64(acc_out, ssum / (double)(PP * m));
    }
}

__global__ void finalize_kernel(const double* __restrict__ acc,
                                float* __restrict__ out) {
    out[0] = -(float)acc[0];
}

extern "C" void kernel_launch(void* const* d_in, const int* in_sizes, int n_in,
                              void* d_out, int out_size, void* d_ws, size_t ws_size,
                              hipStream_t stream) {
    const float* x = (const float*)d_in[0];
    const float* W = (const float*)d_in[1];
    const int* perms = (const int*)d_in[2];

    char* ws = (char*)d_ws;
    float* Gf = (float*)ws;                   // 4096 f32 (16 KB)
    double* acc = (double*)(ws + 16384);      // 1 f64
    float* part = (float*)(ws + 32768);       // npart * 16 KB

    int npart = 128;
    {
        size_t avail = (ws_size > 32768) ? (ws_size - 32768) : 0;
        int fit = (int)(avail / (D * D * sizeof(float)));
        if (fit < npart) npart = fit;
        if (npart < 1) npart = 1;
        if (npart > NBLK) npart = NBLK;
    }

    hipMemsetAsync(acc, 0, sizeof(double), stream);
    gram_kernel<<<npart, 256, 0, stream>>>(x, part, npart);
    reduce_kernel<<<16, 256, 0, stream>>>(part, npart, Gf);
    pair_kernel<<<D * PP, 256, 0, stream>>>(W, perms, Gf, acc);
    finalize_kernel<<<1, 1, 0, stream>>>(acc, (float*)d_out);
}

// Round 3
// 140.338 us; speedup vs baseline: 1.9885x; 1.0534x over previous
//
#include <hip/hip_runtime.h>
#include <math.h>

#define D 64
#define K 16
#define PP 2
#define NN 65536
#define LOG2PI 1.8378770664093454
#define NOISE 0.1  /* 1/BETA */

#ifdef __HIP_PLATFORM_AMD__
#define ATOMIC_ADD_F64(p, v) unsafeAtomicAdd((p), (v))
#else
#define ATOMIC_ADD_F64(p, v) atomicAdd((p), (v))
#endif

// ---------------- Gram partials: per-block 64x64 f32 tile, no atomics --------
#define RCHUNK 128
#define NCH (NN / RCHUNK)  // 512 chunks of 128 rows

__global__ __launch_bounds__(256) void gram_kernel(const float* __restrict__ x,
                                                   float* __restrict__ part,
                                                   int npart) {
    __shared__ float xs[RCHUNK * D];  // 32 KB stage
    const int tid = threadIdx.x;
    const int ib = (tid >> 4) << 2;
    const int jb = (tid & 15) << 2;
    float acc[4][4];
#pragma unroll
    for (int u = 0; u < 4; ++u)
#pragma unroll
        for (int v = 0; v < 4; ++v) acc[u][v] = 0.0f;

    for (int cb = blockIdx.x; cb < NCH; cb += npart) {
        const float4* src = (const float4*)(x + (size_t)cb * RCHUNK * D);
        float4* dst = (float4*)xs;
#pragma unroll
        for (int u = 0; u < 8; ++u)
            dst[tid + 256 * u] = src[tid + 256 * u];
        __syncthreads();
#pragma unroll 4
        for (int r = 0; r < RCHUNK; ++r) {
            const float4 xi = *(const float4*)&xs[r * D + ib];
            const float4 xj = *(const float4*)&xs[r * D + jb];
            float a0[4] = {xi.x, xi.y, xi.z, xi.w};
            float b0[4] = {xj.x, xj.y, xj.z, xj.w};
#pragma unroll
            for (int u = 0; u < 4; ++u)
#pragma unroll
                for (int v = 0; v < 4; ++v)
                    acc[u][v] = fmaf(a0[u], b0[v], acc[u][v]);
        }
        __syncthreads();
    }
    float* p = part + (size_t)blockIdx.x * (D * D);
#pragma unroll
    for (int u = 0; u < 4; ++u)
#pragma unroll
        for (int v = 0; v < 4; ++v)
            p[(ib + u) * D + (jb + v)] = acc[u][v];
}

__global__ __launch_bounds__(256) void reduce_kernel(const float* __restrict__ part,
                                                     int npart,
                                                     float* __restrict__ Gf) {
    const int e = blockIdx.x * 256 + threadIdx.x;  // 4096 entries, grid=16
    double s0 = 0.0, s1 = 0.0, s2 = 0.0, s3 = 0.0;
    int b = 0;
    for (; b + 4 <= npart; b += 4) {
        s0 += (double)part[(size_t)(b + 0) * (D * D) + e];
        s1 += (double)part[(size_t)(b + 1) * (D * D) + e];
        s2 += (double)part[(size_t)(b + 2) * (D * D) + e];
        s3 += (double)part[(size_t)(b + 3) * (D * D) + e];
    }
    for (; b < npart; ++b) s0 += (double)part[(size_t)b * (D * D) + e];
    Gf[e] = (float)((s0 + s1) + (s2 + s3));
}

// ---------------- Per (a,p) pair via Woodbury (M is 16x16) ----------------
__global__ __launch_bounds__(256) void pair_kernel(const float* __restrict__ W,
                                                   const int* __restrict__ perms,
                                                   const float* __restrict__ Gf,
                                                   double* __restrict__ acc_out) {
    const int pair = blockIdx.x;   // a*P + p
    const int m = pair / PP + 1;   // a+1
    const int tid = threadIdx.x;

    __shared__ int perm[D];
    __shared__ float Wp[D][K + 1];
    __shared__ float Gp[D][D + 1];
    __shared__ double Maug[K][2 * K + 1];  // [M | I] -> [I | M^-1]
    __shared__ double U[K][D + 1];         // U[:,j] = M^-1 w_j
    __shared__ double Y[K][D + 1];         // Y = Wr^T Gp[m:,:]
    __shared__ double Z[K][K + 1];         // Z = Y[:,m:] Wr
    __shared__ double qp[4][D];
    __shared__ double vp[4][D];
    __shared__ double red[D];

    if (tid < D) perm[tid] = perms[pair * D + tid];
    __syncthreads();
    for (int e = tid; e < D * K; e += 256) {
        int i = e >> 4, k = e & (K - 1);
        Wp[i][k] = W[perm[i] * K + k];
    }
    for (int e = tid; e < D * D; e += 256) {
        int i = e >> 6, t = e & 63;
        Gp[i][t] = Gf[perm[i] * D + perm[t]];
    }
    __syncthreads();

    // M = eps*I + Wr^T Wr  (16x16, f64), augmented with I
    {
        int k1 = tid >> 4, k2 = tid & 15;
        if (tid < K * K) {
            double s = (k1 == k2) ? NOISE : 0.0;
            for (int sr = m; sr < D; ++sr)
                s += (double)Wp[sr][k1] * (double)Wp[sr][k2];
            Maug[k1][k2] = s;
            Maug[k1][K + k2] = (k1 == k2) ? 1.0 : 0.0;
        }
    }
    __syncthreads();

    // Gauss-Jordan invert M (SPD, no pivot). 16 rows x 32 cols, 2 rows/thread.
    {
        const int c = tid & 31;
        const int r0 = tid >> 5;  // 0..7; also handles r0+8
        for (int k = 0; k < K; ++k) {
            double a0 = Maug[r0][c], a1 = Maug[r0 + 8][c];
            double f0 = Maug[r0][k], f1 = Maug[r0 + 8][k];
            double srow = Maug[k][c] / Maug[k][k];
            __syncthreads();
            Maug[r0][c] = (r0 == k) ? srow : a0 - f0 * srow;
            Maug[r0 + 8][c] = (r0 + 8 == k) ? srow : a1 - f1 * srow;
            __syncthreads();
        }
    }

    // U[k][j] = sum_k2 Minv[k][k2] * Wp[j][k2]
    {
        const int j = tid & 63;
        const int kb = tid >> 6;  // 0..3
#pragma unroll
        for (int u = 0; u < 4; ++u) {
            int k = kb + 4 * u;
            double s = 0.0;
#pragma unroll
            for (int k2 = 0; k2 < K; ++k2)
                s += Maug[k][K + k2] * (double)Wp[j][k2];
            U[k][j] = s;
        }
        // Y[k][j] = sum_{s>=m} Wp[s][k] * Gp[s][j]
#pragma unroll
        for (int u = 0; u < 4; ++u) {
            int k = kb + 4 * u;
            double s = 0.0;
            for (int sr = m; sr < D; ++sr)
                s += (double)Wp[sr][k] * (double)Gp[sr][j];
            Y[k][j] = s;
        }
    }
    __syncthreads();

    // Z[k1][k2] = sum_{s>=m} Y[k1][s] * Wp[s][k2]
    {
        int k1 = tid >> 4, k2 = tid & 15;
        if (tid < K * K) {
            double s = 0.0;
            for (int sr = m; sr < D; ++sr)
                s += Y[k1][sr] * (double)Wp[sr][k2];
            Z[k1][k2] = s;
        }
    }
    __syncthreads();

    // per-j partials: dv = w_j.u_j ; t1 = u_j.Y[:,j] ; t2 = u_j^T Z u_j
    {
        const int lane4 = tid & 3;
        const int j = tid >> 2;
        double dv = 0.0, t1 = 0.0, t2 = 0.0;
        for (int k1 = lane4; k1 < K; k1 += 4) {
            double uj = U[k1][j];
            dv += (double)Wp[j][k1] * uj;
            t1 += uj * Y[k1][j];
            double zs = 0.0;
#pragma unroll
            for (int k2 = 0; k2 < K; ++k2) zs += Z[k1][k2] * U[k2][j];
            t2 += uj * zs;
        }
        vp[lane4][j] = dv;
        qp[lane4][j] = -2.0 * t1 + t2;
    }
    __syncthreads();

    if (tid < D) {
        const int j = tid;
        double tj = 0.0;
        if (j < m) {
            double dv = vp[0][j] + vp[1][j] + vp[2][j] + vp[3][j];
            double v = NOISE * (1.0 + dv);
            double q = (double)Gp[j][j] + qp[0][j] + qp[1][j] + qp[2][j] + qp[3][j];
            tj = -0.5 * log(v) - 0.5 * LOG2PI - 0.5 * q / (v * (double)NN);
        }
        red[j] = tj;
    }
    __syncthreads();
    if (tid == 0) {
        double ssum = 0.0;
        for (int j = 0; j < D; ++j) ssum += red[j];
        ATOMIC_ADD_F64(acc_out, ssum / (double)(PP * m));
    }
}

__global__ void finalize_kernel(const double* __restrict__ acc,
                                float* __restrict__ out) {
    out[0] = -(float)acc[0];
}

extern "C" void kernel_launch(void* const* d_in, const int* in_sizes, int n_in,
                              void* d_out, int out_size, void* d_ws, size_t ws_size,
                              hipStream_t stream) {
    const float* x = (const float*)d_in[0];
    const float* W = (const float*)d_in[1];
    const int* perms = (const int*)d_in[2];

    char* ws = (char*)d_ws;
    float* Gf = (float*)ws;                   // 4096 f32 (16 KB)
    double* acc = (double*)(ws + 16384);      // 1 f64
    float* part = (float*)(ws + 32768);       // npart * 16 KB

    int npart = NCH;  // 512 blocks: 2 per CU
    {
        size_t avail = (ws_size > 32768) ? (ws_size - 32768) : 0;
        int fit = (int)(avail / (D * D * sizeof(float)));
        if (fit < npart) npart = fit;
        if (npart < 1) npart = 1;
    }

    hipMemsetAsync(acc, 0, sizeof(double), stream);
    gram_kernel<<<npart, 256, 0, stream>>>(x, part, npart);
    reduce_kernel<<<16, 256, 0, stream>>>(part, npart, Gf);
    pair_kernel<<<D * PP, 256, 0, stream>>>(W, perms, Gf, acc);
    finalize_kernel<<<1, 1, 0, stream>>>(acc, (float*)d_out);
}

// Round 4
// 135.587 us; speedup vs baseline: 2.0582x; 1.0350x over previous
//
#include <hip/hip_runtime.h>
#include <math.h>

#define D 64
#define K 16
#define PP 2
#define NN 65536
#define LOG2PI 1.8378770664093454
#define NOISE 0.1 /* 1/BETA */

// ---------------- Gram partials: per-block 64x64 f32 tile, no atomics --------
#define RCHUNK 128
#define NCH (NN / RCHUNK) // 512 chunks of 128 rows

__global__ __launch_bounds__(256) void gram_kernel(const float* __restrict__ x,
                                                   float* __restrict__ part,
                                                   int npart,
                                                   float* __restrict__ out) {
    if (blockIdx.x == 0 && threadIdx.x == 0) out[0] = 0.0f;  // pair_kernel accumulates here
    __shared__ float xs[RCHUNK * D];  // 32 KB stage
    const int tid = threadIdx.x;
    const int ib = (tid >> 4) << 2;
    const int jb = (tid & 15) << 2;
    float acc[4][4];
#pragma unroll
    for (int u = 0; u < 4; ++u)
#pragma unroll
        for (int v = 0; v < 4; ++v) acc[u][v] = 0.0f;

    for (int cb = blockIdx.x; cb < NCH; cb += npart) {
        const float4* src = (const float4*)(x + (size_t)cb * RCHUNK * D);
        float4* dst = (float4*)xs;
#pragma unroll
        for (int u = 0; u < 8; ++u)
            dst[tid + 256 * u] = src[tid + 256 * u];
        __syncthreads();
#pragma unroll 4
        for (int r = 0; r < RCHUNK; ++r) {
            const float4 xi = *(const float4*)&xs[r * D + ib];
            const float4 xj = *(const float4*)&xs[r * D + jb];
            float a0[4] = {xi.x, xi.y, xi.z, xi.w};
            float b0[4] = {xj.x, xj.y, xj.z, xj.w};
#pragma unroll
            for (int u = 0; u < 4; ++u)
#pragma unroll
                for (int v = 0; v < 4; ++v)
                    acc[u][v] = fmaf(a0[u], b0[v], acc[u][v]);
        }
        __syncthreads();
    }
    float* p = part + (size_t)blockIdx.x * (D * D);
#pragma unroll
    for (int u = 0; u < 4; ++u)
#pragma unroll
        for (int v = 0; v < 4; ++v)
            p[(ib + u) * D + (jb + v)] = acc[u][v];
}

__global__ __launch_bounds__(256) void reduce_kernel(const float* __restrict__ part,
                                                     int npart,
                                                     float* __restrict__ Gf) {
    const int e = blockIdx.x * 256 + threadIdx.x;  // 4096 entries, grid=16
    double s0 = 0.0, s1 = 0.0, s2 = 0.0, s3 = 0.0;
    int b = 0;
    for (; b + 4 <= npart; b += 4) {
        s0 += (double)part[(size_t)(b + 0) * (D * D) + e];
        s1 += (double)part[(size_t)(b + 1) * (D * D) + e];
        s2 += (double)part[(size_t)(b + 2) * (D * D) + e];
        s3 += (double)part[(size_t)(b + 3) * (D * D) + e];
    }
    for (; b < npart; ++b) s0 += (double)part[(size_t)b * (D * D) + e];
    Gf[e] = (float)((s0 + s1) + (s2 + s3));
}

// ---------------- Per (a,p) pair via Woodbury (M is 16x16) ----------------
// GJ inversion of M done entirely in registers on wave 0 (shuffles, no barriers)
// while waves 1-3 compute Z. Block barrier count: 6.
__global__ __launch_bounds__(256) void pair_kernel(const float* __restrict__ W,
                                                   const int* __restrict__ perms,
                                                   const float* __restrict__ Gf,
                                                   float* __restrict__ out) {
    const int pair = blockIdx.x;  // a*P + p
    const int m = pair / PP + 1;  // a+1
    const int tid = threadIdx.x;
    const int wave = tid >> 6;
    const int lane = tid & 63;

    __shared__ int perm[D];
    __shared__ float Wp[D][K + 1];
    __shared__ float Gp[D][D + 1];
    __shared__ double Mlds[K][K + 1];
    __shared__ double Minv[K][K + 1];
    __shared__ double U[K][D + 1];  // U[:,j] = M^-1 w_j
    __shared__ double Y[K][D + 1];  // Y = Wr^T Gp[m:,:]
    __shared__ double Z[K][K + 1];  // Z = Y[:,m:] Wr
    __shared__ double qp[4][D];
    __shared__ double vp[4][D];

    if (tid < D) perm[tid] = perms[pair * D + tid];
    __syncthreads();  // B1
    for (int e = tid; e < D * K; e += 256) {
        int i = e >> 4, k = e & (K - 1);
        Wp[i][k] = W[perm[i] * K + k];
    }
    for (int e = tid; e < D * D; e += 256) {
        int i = e >> 6, t = e & 63;
        Gp[i][t] = Gf[perm[i] * D + perm[t]];
    }
    __syncthreads();  // B2

    // Phase A: build M (1 entry/thread) and Y (4 entries/thread)
    {
        int k1 = tid >> 4, k2 = tid & 15;
        double s = (k1 == k2) ? NOISE : 0.0;
        for (int sr = m; sr < D; ++sr)
            s += (double)Wp[sr][k1] * (double)Wp[sr][k2];
        Mlds[k1][k2] = s;
    }
    {
        const int j = tid & 63;
        const int kb = tid >> 6;
#pragma unroll
        for (int u = 0; u < 4; ++u) {
            int k = kb + 4 * u;
            double s = 0.0;
            for (int sr = m; sr < D; ++sr)
                s += (double)Wp[sr][k] * (double)Gp[sr][j];
            Y[k][j] = s;
        }
    }
    __syncthreads();  // B3

    // Phase B: wave 0 -> register GJ of [M|I]; waves 1-3 -> Z = Y[:,m:] Wr
    if (wave == 0) {
        const int r = lane & 15;   // my row
        const int ch = lane >> 4;  // my 8-col chunk of the 16x32 augmented matrix
        double a[8];
#pragma unroll
        for (int j = 0; j < 8; ++j) {
            if (ch < 2) a[j] = Mlds[r][ch * 8 + j];
            else a[j] = ((ch - 2) * 8 + j == r) ? 1.0 : 0.0;
        }
        for (int k = 0; k < K; ++k) {
            const int chk = k >> 3;
            const int rk = k & 7;      // uniform register index holding col k
            double colk = a[rk];
            double fme = __shfl(colk, (chk << 4) | r, 64);  // M[r][k]
            double piv = __shfl(colk, (chk << 4) | k, 64);  // M[k][k]
            double pinv = 1.0 / piv;
            double p[8];
#pragma unroll
            for (int j = 0; j < 8; ++j)
                p[j] = __shfl(a[j], (ch << 4) | k, 64) * pinv;  // scaled pivot row
            if (r == k) {
#pragma unroll
                for (int j = 0; j < 8; ++j) a[j] = p[j];
            } else {
#pragma unroll
                for (int j = 0; j < 8; ++j) a[j] -= fme * p[j];
            }
        }
        if (ch >= 2)
#pragma unroll
            for (int j = 0; j < 8; ++j) Minv[r][(ch - 2) * 8 + j] = a[j];
    } else {
        for (int e = tid - 64; e < K * K; e += 192) {
            int k1 = e >> 4, k2 = e & 15;
            double s = 0.0;
            for (int sr = m; sr < D; ++sr)
                s += Y[k1][sr] * (double)Wp[sr][k2];
            Z[k1][k2] = s;
        }
    }
    __syncthreads();  // B4

    // Phase C: U[k][j] = sum_k2 Minv[k][k2] * Wp[j][k2]
    {
        const int j = tid & 63;
        const int kb = tid >> 6;
#pragma unroll
        for (int u = 0; u < 4; ++u) {
            int k = kb + 4 * u;
            double s = 0.0;
#pragma unroll
            for (int k2 = 0; k2 < K; ++k2)
                s += Minv[k][k2] * (double)Wp[j][k2];
            U[k][j] = s;
        }
    }
    __syncthreads();  // B5

    // Phase D: per-j partials: dv = w_j.u_j ; t1 = u_j.Y[:,j] ; t2 = u_j^T Z u_j
    {
        const int lane4 = tid & 3;
        const int j = tid >> 2;
        double dv = 0.0, t1 = 0.0, t2 = 0.0;
        for (int k1 = lane4; k1 < K; k1 += 4) {
            double uj = U[k1][j];
            dv += (double)Wp[j][k1] * uj;
            t1 += uj * Y[k1][j];
            double zs = 0.0;
#pragma unroll
            for (int k2 = 0; k2 < K; ++k2) zs += Z[k1][k2] * U[k2][j];
            t2 += uj * zs;
        }
        vp[lane4][j] = dv;
        qp[lane4][j] = -2.0 * t1 + t2;
    }
    __syncthreads();  // B6

    // Phase E: per-row terms + wave-0 shuffle reduction + one f32 atomic
    if (tid < D) {
        const int j = tid;
        double tj = 0.0;
        if (j < m) {
            double dv = vp[0][j] + vp[1][j] + vp[2][j] + vp[3][j];
            double v = NOISE * (1.0 + dv);
            double q = (double)Gp[j][j] + qp[0][j] + qp[1][j] + qp[2][j] + qp[3][j];
            tj = -0.5 * log(v) - 0.5 * LOG2PI - 0.5 * q / (v * (double)NN);
        }
#pragma unroll
        for (int off = 32; off > 0; off >>= 1) tj += __shfl_down(tj, off, 64);
        if (tid == 0) atomicAdd(out, (float)(-tj / (double)(PP * m)));
    }
}

extern "C" void kernel_launch(void* const* d_in, const int* in_sizes, int n_in,
                              void* d_out, int out_size, void* d_ws, size_t ws_size,
                              hipStream_t stream) {
    const float* x = (const float*)d_in[0];
    const float* W = (const float*)d_in[1];
    const int* perms = (const int*)d_in[2];

    char* ws = (char*)d_ws;
    float* Gf = (float*)ws;               // 4096 f32 (16 KB)
    float* part = (float*)(ws + 32768);   // npart * 16 KB

    int npart = NCH;  // 512 blocks: 2 per CU
    {
        size_t avail = (ws_size > 32768) ? (ws_size - 32768) : 0;
        int fit = (int)(avail / (D * D * sizeof(float)));
        if (fit < npart) npart = fit;
        if (npart < 1) npart = 1;
    }

    gram_kernel<<<npart, 256, 0, stream>>>(x, part, npart, (float*)d_out);
    reduce_kernel<<<16, 256, 0, stream>>>(part, npart, Gf);
    pair_kernel<<<D * PP, 256, 0, stream>>>(W, perms, Gf, (float*)d_out);
}

// Round 5
// 107.846 us; speedup vs baseline: 2.5876x; 1.2572x over previous
//
#include <hip/hip_runtime.h>
#include <math.h>

#define D 64
#define K 16
#define PP 2
#define NN 65536
#define LOG2PI 1.8378770664093454
#define NOISE 0.1 /* 1/BETA */

// ---------------- Gram partials: per-block 64x64 f32 tile, no atomics --------
#define RCHUNK 128
#define NCH (NN / RCHUNK) // 512 chunks of 128 rows

__global__ __launch_bounds__(256) void gram_kernel(const float* __restrict__ x,
                                                   float* __restrict__ part,
                                                   int npart,
                                                   float* __restrict__ out) {
    if (blockIdx.x == 0 && threadIdx.x == 0) out[0] = 0.0f;  // pair_kernel accumulates here
    __shared__ float xs[RCHUNK * D];  // 32 KB stage
    const int tid = threadIdx.x;
    const int ib = (tid >> 4) << 2;
    const int jb = (tid & 15) << 2;
    float acc[4][4];
#pragma unroll
    for (int u = 0; u < 4; ++u)
#pragma unroll
        for (int v = 0; v < 4; ++v) acc[u][v] = 0.0f;

    for (int cb = blockIdx.x; cb < NCH; cb += npart) {
        const float4* src = (const float4*)(x + (size_t)cb * RCHUNK * D);
        float4* dst = (float4*)xs;
#pragma unroll
        for (int u = 0; u < 8; ++u)
            dst[tid + 256 * u] = src[tid + 256 * u];
        __syncthreads();
#pragma unroll 4
        for (int r = 0; r < RCHUNK; ++r) {
            const float4 xi = *(const float4*)&xs[r * D + ib];
            const float4 xj = *(const float4*)&xs[r * D + jb];
            float a0[4] = {xi.x, xi.y, xi.z, xi.w};
            float b0[4] = {xj.x, xj.y, xj.z, xj.w};
#pragma unroll
            for (int u = 0; u < 4; ++u)
#pragma unroll
                for (int v = 0; v < 4; ++v)
                    acc[u][v] = fmaf(a0[u], b0[v], acc[u][v]);
        }
        __syncthreads();
    }
    float* p = part + (size_t)blockIdx.x * (D * D);
#pragma unroll
    for (int u = 0; u < 4; ++u)
#pragma unroll
        for (int v = 0; v < 4; ++v)
            p[(ib + u) * D + (jb + v)] = acc[u][v];
}

// 256 blocks x 16 entries; 16 threads split the npart partials per entry.
// Exact partition, deterministic, no atomics.
__global__ __launch_bounds__(256) void reduce_kernel(const float* __restrict__ part,
                                                     int npart,
                                                     float* __restrict__ Gf) {
    const int tid = threadIdx.x;
    const int le = tid >> 4;   // 0..15 local entry
    const int sub = tid & 15;  // partial-subset index
    const int e = blockIdx.x * 16 + le;
    __shared__ double ps[16][17];
    double s0 = 0.0, s1 = 0.0;
    for (int b = sub; b < npart; b += 32)
        s0 += (double)part[(size_t)b * (D * D) + e];
    for (int b = sub + 16; b < npart; b += 32)
        s1 += (double)part[(size_t)b * (D * D) + e];
    ps[le][sub] = s0 + s1;
    __syncthreads();
    if (sub == 0) {
        double t = 0.0;
#pragma unroll
        for (int i = 0; i < 16; ++i) t += ps[le][i];
        Gf[e] = (float)t;
    }
}

// ---------------- Per (a,p) pair via Woodbury (M is 16x16) ----------------
// GJ inversion of M done entirely in registers on wave 0 (shuffles, no barriers)
// while waves 1-3 compute Z. Block barrier count: 6.
__global__ __launch_bounds__(256) void pair_kernel(const float* __restrict__ W,
                                                   const int* __restrict__ perms,
                                                   const float* __restrict__ Gf,
                                                   float* __restrict__ out) {
    const int pair = blockIdx.x;  // a*P + p
    const int m = pair / PP + 1;  // a+1
    const int tid = threadIdx.x;
    const int wave = tid >> 6;
    const int lane = tid & 63;

    __shared__ int perm[D];
    __shared__ float Wp[D][K + 1];
    __shared__ float Gp[D][D + 1];
    __shared__ double Mlds[K][K + 1];
    __shared__ double Minv[K][K + 1];
    __shared__ double U[K][D + 1];  // U[:,j] = M^-1 w_j
    __shared__ double Y[K][D + 1];  // Y = Wr^T Gp[m:,:]
    __shared__ double Z[K][K + 1];  // Z = Y[:,m:] Wr
    __shared__ double qp[4][D];
    __shared__ double vp[4][D];

    if (tid < D) perm[tid] = perms[pair * D + tid];
    __syncthreads();  // B1
    for (int e = tid; e < D * K; e += 256) {
        int i = e >> 4, k = e & (K - 1);
        Wp[i][k] = W[perm[i] * K + k];
    }
    for (int e = tid; e < D * D; e += 256) {
        int i = e >> 6, t = e & 63;
        Gp[i][t] = Gf[perm[i] * D + perm[t]];
    }
    __syncthreads();  // B2

    // Phase A: build M (1 entry/thread) and Y (4 entries/thread)
    {
        int k1 = tid >> 4, k2 = tid & 15;
        double s = (k1 == k2) ? NOISE : 0.0;
        for (int sr = m; sr < D; ++sr)
            s += (double)Wp[sr][k1] * (double)Wp[sr][k2];
        Mlds[k1][k2] = s;
    }
    {
        const int j = tid & 63;
        const int kb = tid >> 6;
#pragma unroll
        for (int u = 0; u < 4; ++u) {
            int k = kb + 4 * u;
            double s = 0.0;
            for (int sr = m; sr < D; ++sr)
                s += (double)Wp[sr][k] * (double)Gp[sr][j];
            Y[k][j] = s;
        }
    }
    __syncthreads();  // B3

    // Phase B: wave 0 -> register GJ of [M|I]; waves 1-3 -> Z = Y[:,m:] Wr
    if (wave == 0) {
        const int r = lane & 15;   // my row
        const int ch = lane >> 4;  // my 8-col chunk of the 16x32 augmented matrix
        double a[8];
#pragma unroll
        for (int j = 0; j < 8; ++j) {
            if (ch < 2) a[j] = Mlds[r][ch * 8 + j];
            else a[j] = ((ch - 2) * 8 + j == r) ? 1.0 : 0.0;
        }
        for (int k = 0; k < K; ++k) {
            const int chk = k >> 3;
            const int rk = k & 7;      // uniform register index holding col k
            double colk = a[rk];
            double fme = __shfl(colk, (chk << 4) | r, 64);  // M[r][k]
            double piv = __shfl(colk, (chk << 4) | k, 64);  // M[k][k]
            double pinv = 1.0 / piv;
            double p[8];
#pragma unroll
            for (int j = 0; j < 8; ++j)
                p[j] = __shfl(a[j], (ch << 4) | k, 64) * pinv;  // scaled pivot row
            if (r == k) {
#pragma unroll
                for (int j = 0; j < 8; ++j) a[j] = p[j];
            } else {
#pragma unroll
                for (int j = 0; j < 8; ++j) a[j] -= fme * p[j];
            }
        }
        if (ch >= 2)
#pragma unroll
            for (int j = 0; j < 8; ++j) Minv[r][(ch - 2) * 8 + j] = a[j];
    } else {
        for (int e = tid - 64; e < K * K; e += 192) {
            int k1 = e >> 4, k2 = e & 15;
            double s = 0.0;
            for (int sr = m; sr < D; ++sr)
                s += Y[k1][sr] * (double)Wp[sr][k2];
            Z[k1][k2] = s;
        }
    }
    __syncthreads();  // B4

    // Phase C: U[k][j] = sum_k2 Minv[k][k2] * Wp[j][k2]
    {
        const int j = tid & 63;
        const int kb = tid >> 6;
#pragma unroll
        for (int u = 0; u < 4; ++u) {
            int k = kb + 4 * u;
            double s = 0.0;
#pragma unroll
            for (int k2 = 0; k2 < K; ++k2)
                s += Minv[k][k2] * (double)Wp[j][k2];
            U[k][j] = s;
        }
    }
    __syncthreads();  // B5

    // Phase D: per-j partials: dv = w_j.u_j ; t1 = u_j.Y[:,j] ; t2 = u_j^T Z u_j
    {
        const int lane4 = tid & 3;
        const int j = tid >> 2;
        double dv = 0.0, t1 = 0.0, t2 = 0.0;
        for (int k1 = lane4; k1 < K; k1 += 4) {
            double uj = U[k1][j];
            dv += (double)Wp[j][k1] * uj;
            t1 += uj * Y[k1][j];
            double zs = 0.0;
#pragma unroll
            for (int k2 = 0; k2 < K; ++k2) zs += Z[k1][k2] * U[k2][j];
            t2 += uj * zs;
        }
        vp[lane4][j] = dv;
        qp[lane4][j] = -2.0 * t1 + t2;
    }
    __syncthreads();  // B6

    // Phase E: per-row terms + wave-0 shuffle reduction + one f32 atomic
    if (tid < D) {
        const int j = tid;
        double tj = 0.0;
        if (j < m) {
            double dv = vp[0][j] + vp[1][j] + vp[2][j] + vp[3][j];
            double v = NOISE * (1.0 + dv);
            double q = (double)Gp[j][j] + qp[0][j] + qp[1][j] + qp[2][j] + qp[3][j];
            tj = -0.5 * log(v) - 0.5 * LOG2PI - 0.5 * q / (v * (double)NN);
        }
#pragma unroll
        for (int off = 32; off > 0; off >>= 1) tj += __shfl_down(tj, off, 64);
        if (tid == 0) atomicAdd(out, (float)(-tj / (double)(PP * m)));
    }
}

extern "C" void kernel_launch(void* const* d_in, const int* in_sizes, int n_in,
                              void* d_out, int out_size, void* d_ws, size_t ws_size,
                              hipStream_t stream) {
    const float* x = (const float*)d_in[0];
    const float* W = (const float*)d_in[1];
    const int* perms = (const int*)d_in[2];

    char* ws = (char*)d_ws;
    float* Gf = (float*)ws;               // 4096 f32 (16 KB)
    float* part = (float*)(ws + 32768);   // npart * 16 KB

    int npart = NCH;  // 512 blocks: 2 per CU
    {
        size_t avail = (ws_size > 32768) ? (ws_size - 32768) : 0;
        int fit = (int)(avail / (D * D * sizeof(float)));
        if (fit < npart) npart = fit;
        if (npart < 1) npart = 1;
    }

    gram_kernel<<<npart, 256, 0, stream>>>(x, part, npart, (float*)d_out);
    reduce_kernel<<<256, 256, 0, stream>>>(part, npart, Gf);
    pair_kernel<<<D * PP, 256, 0, stream>>>(W, perms, Gf, (float*)d_out);
}